// Round 4
// baseline (342.987 us; speedup 1.0000x reference)
//
#include <hip/hip_runtime.h>

// ---- static config (matches reference) ----
constexpr int kNImgs   = 9;
constexpr int kC       = 24;
constexpr int kHF      = 112, kWF = 112;
constexpr int kHD      = 56,  kWD = 56;
constexpr int kNPix    = kHD * kWD;              // 3136
constexpr int kNPlanes = 64;
constexpr int kPtsPerRef = kNPlanes * kNPix;     // 200704 = 784 * 256
constexpr int kEdgesPerRef = 8;
constexpr int kNEdges  = kNImgs * kEdgesPerRef;  // 72
constexpr int kFeatPix = kHF * kWF;              // 12544
constexpr int kFeatPerImg = kC * kFeatPix;       // 301056

typedef _Float16 half8  __attribute__((ext_vector_type(8)));
typedef _Float16 half2v __attribute__((ext_vector_type(2)));
typedef unsigned int uint4v __attribute__((ext_vector_type(4)));

#if __has_builtin(__builtin_amdgcn_fdot2)
__device__ inline float fdot2(half2v a, half2v b, float c) {
  return __builtin_amdgcn_fdot2(a, b, c, false);
}
#else
__device__ inline float fdot2(half2v a, half2v b, float c) {
  return c + (float)a[0] * (float)b[0] + (float)a[1] * (float)b[1];
}
#endif

__device__ inline half2v u2h(unsigned int u) {
  union { unsigned int u; half2v h; } cv; cv.u = u; return cv.h;
}

// ---------- small 3x3 helpers ----------
__device__ inline void mm3(const float* A, const float* B, float* C) {
#pragma unroll
  for (int i = 0; i < 3; ++i)
#pragma unroll
    for (int j = 0; j < 3; ++j)
      C[i*3+j] = A[i*3+0]*B[0*3+j] + A[i*3+1]*B[1*3+j] + A[i*3+2]*B[2*3+j];
}

__device__ inline void inv3(const float* A, float* I) {
  float a=A[0],b=A[1],c=A[2],d=A[3],e=A[4],f=A[5],g=A[6],h=A[7],i=A[8];
  float c00 = e*i - f*h;
  float c01 = -(d*i - f*g);
  float c02 = d*h - e*g;
  float det = a*c00 + b*c01 + c*c02;
  float r = 1.0f / det;
  I[0] = c00*r;           I[1] = (c*h - b*i)*r;  I[2] = (b*f - c*e)*r;
  I[3] = c01*r;           I[4] = (a*i - c*g)*r;  I[5] = (c*d - a*f)*r;
  I[6] = c02*r;           I[7] = (b*g - a*h)*r;  I[8] = (a*e - b*d)*r;
}

// ---------- pack feats [N,C,HF,WF] f32 -> [N,HF,WF,C] of half2(f[x], f[x+1]) ----------
// one thread per (n, y, x): reads 24 strided f32 pairs, writes 96 contiguous bytes.
__global__ __launch_bounds__(256)
void pack_feats_kernel(const float* __restrict__ f, _Float16* __restrict__ fp) {
  int idx = blockIdx.x * 256 + threadIdx.x;
  if (idx >= kNImgs * kFeatPix) return;
  int n  = idx / kFeatPix;
  int yx = idx - n * kFeatPix;
  int x  = yx % kWF;
  int xn = (x < kWF - 1) ? 1 : 0;   // duplicate last column
  const float* src = f + (size_t)n * kFeatPerImg + yx;
  _Float16* dst = fp + (size_t)idx * (2 * kC);
  half8 buf[6];
#pragma unroll
  for (int i = 0; i < 6; ++i) {
#pragma unroll
    for (int k = 0; k < 4; ++k) {
      int c = 4*i + k;
      float A = src[(size_t)c * kFeatPix];
      float B = src[(size_t)c * kFeatPix + xn];
      buf[i][2*k]   = (_Float16)A;
      buf[i][2*k+1] = (_Float16)B;
    }
    *((half8*)dst + i) = buf[i];
  }
}

// ---------- main fused kernel ----------
// thread = one (ref n, plane d, pixel p) point; writes 24 channel variances.
// featsP layout: [N][HF][WF][C] elements of half2 = (f[y][x], f[y][x+1 clamped])
template <bool TR>
__global__ __launch_bounds__(256)
void psv_var_kernel(const float* __restrict__ feats,      // [N,C,HF,WF] f32 (used if !TR)
                    const _Float16* __restrict__ featsP,  // packed pairs (used if TR)
                    const float* __restrict__ rotmats,    // [N,3,3]
                    const float* __restrict__ tvecs,      // [N,3]
                    const float* __restrict__ Kmat,       // [N,3,3]
                    const int*   __restrict__ edges,      // [2,72]
                    float* __restrict__ out) {            // [N,C,D,HD,WD]
  __shared__ float sM[kEdgesPerRef][9];
  __shared__ float sB[kEdgesPerRef][3];
  __shared__ int   sSrc[kEdgesPerRef];

  // XCD-contiguous swizzle: 7056 blocks = 8 * 882 exactly -> bijective.
  const int nwg = gridDim.x;
  int bid = blockIdx.x;
  if ((nwg & 7) == 0) {
    const int cpx = nwg >> 3;
    bid = (bid & 7) * cpx + (bid >> 3);
  }

  const int tid = bid * 256 + threadIdx.x;
  const int n = tid / kPtsPerRef;  // block never straddles refs (200704 % 256 == 0)

  if (threadIdx.x < kEdgesPerRef) {
    const int e  = n * kEdgesPerRef + threadIdx.x;
    const int re = edges[e];            // ref row
    const int se = edges[kNEdges + e];  // src row
    sSrc[threadIdx.x] = se;

    const float* Rr = rotmats + re * 9;
    const float* Rs = rotmats + se * 9;
    const float* Kr = Kmat + re * 9;
    const float* Ks = Kmat + se * 9;
    const float* tr = tvecs + re * 3;
    const float* ts = tvecs + se * 3;

    float RrT[9];
#pragma unroll
    for (int i = 0; i < 3; ++i)
#pragma unroll
      for (int j = 0; j < 3; ++j) RrT[i*3+j] = Rr[j*3+i];

    float Kinv[9], A[9], T1[9], M[9];
    inv3(Kr, Kinv);
    mm3(Rs, RrT, A);       // A = R_src * R_ref^T
    mm3(A, Kinv, T1);
    mm3(Ks, T1, M);        // M = K_src * A * K_ref^-1

    float At0 = A[0]*tr[0] + A[1]*tr[1] + A[2]*tr[2];
    float At1 = A[3]*tr[0] + A[4]*tr[1] + A[5]*tr[2];
    float At2 = A[6]*tr[0] + A[7]*tr[1] + A[8]*tr[2];
    float bv0 = ts[0] - At0, bv1 = ts[1] - At1, bv2 = ts[2] - At2;
#pragma unroll
    for (int i = 0; i < 9; ++i) sM[threadIdx.x][i] = M[i];
#pragma unroll
    for (int i = 0; i < 3; ++i)
      sB[threadIdx.x][i] = Ks[i*3+0]*bv0 + Ks[i*3+1]*bv1 + Ks[i*3+2]*bv2;
  }
  __syncthreads();

  const int local = tid - n * kPtsPerRef;
  const int d = local / kNPix;
  const int p = local - d * kNPix;
  const int h = p / kWD;
  const int w = p - h * kWD;

  const float u = (float)w * (447.0f / 55.0f);   // linspace(0,447,56)
  const float v = (float)h * (447.0f / 55.0f);
  const float depth = 0.5f + 0.05f * (float)d;

  float acc[kC], accsq[kC];
#pragma unroll
  for (int c = 0; c < kC; ++c) { acc[c] = 0.0f; accsq[c] = 0.0f; }

#pragma unroll 2
  for (int j = 0; j < kEdgesPerRef; ++j) {
    const float* M = sM[j];
    const float px = depth * (M[0]*u + M[1]*v + M[2]) + sB[j][0];
    const float py = depth * (M[3]*u + M[4]*v + M[5]) + sB[j][1];
    const float pz = depth * (M[6]*u + M[7]*v + M[8]) + sB[j][2];
    const float rz = 1.0f / (fabsf(pz) + 1e-8f);

    // x = (px/z) * 111/447  (align_corners=True, folded constants)
    const float x = px * rz * (111.0f / 447.0f);
    const float y = py * rz * (111.0f / 447.0f);

    const float x0 = floorf(x), y0 = floorf(y);
    const float wx = x - x0, wy = y - y0;
    const bool vx0 = (x0 >= 0.0f)  && (x0 <= 111.0f);
    const bool vx1 = (x0 >= -1.0f) && (x0 <= 110.0f);
    const bool vy0 = (y0 >= 0.0f)  && (y0 <= 111.0f);
    const bool vy1 = (y0 >= -1.0f) && (y0 <= 110.0f);

    const float wxl = vx0 ? (1.0f - wx) : 0.0f;
    const float wxr = vx1 ? wx : 0.0f;
    const float wy0f = vy0 ? (1.0f - wy) : 0.0f;
    const float wy1f = vy1 ? wy : 0.0f;

    const int xi = (int)fminf(fmaxf(x0, -2.0f), 113.0f);
    const int yi = (int)fminf(fmaxf(y0, -2.0f), 113.0f);
    // pair loaded at x=0 is (f[0], f[1]); when x0 == -1, tap x0+1 = 0 takes wxr in slot 0
    const float a = (xi < 0) ? wxr : wxl;
    const float b = (xi < 0) ? 0.0f : wxr;
    const int xload = min(max(xi, 0), kWF - 1);
    const int yc0 = min(max(yi,     0), kHF - 1);
    const int yc1 = min(max(yi + 1, 0), kHF - 1);

    const int src = sSrc[j];
    if constexpr (TR) {
      half2v wr0 = {(_Float16)(a * wy0f), (_Float16)(b * wy0f)};
      half2v wr1 = {(_Float16)(a * wy1f), (_Float16)(b * wy1f)};
      const _Float16* base = featsP + (size_t)src * kFeatPix * (2 * kC);
      const uint4v* R0 = (const uint4v*)(base + (size_t)(yc0 * kWF + xload) * (2 * kC));
      const uint4v* R1 = (const uint4v*)(base + (size_t)(yc1 * kWF + xload) * (2 * kC));
#pragma unroll
      for (int i = 0; i < 6; ++i) {            // 6 chunks of 4 channel-pairs
        const uint4v q0 = R0[i];
        const uint4v q1 = R1[i];
#pragma unroll
        for (int k = 0; k < 4; ++k) {
          half2v p0 = u2h(q0[k]);
          half2v p1 = u2h(q1[k]);
          float val = fdot2(p1, wr1, fdot2(p0, wr0, 0.0f));
          const int c = 4*i + k;
          acc[c] += val;
          accsq[c] = __builtin_fmaf(val, val, accsq[c]);
        }
      }
    } else {
      const float w00 = wxl * wy0f, w01 = b * wy0f;
      const float w10 = wxl * wy1f, w11 = b * wy1f;
      const int xc0 = xload;
      const int xc1 = min(max(xi + 1, 0), kWF - 1);
      const float* fbase = feats + (size_t)src * kFeatPerImg;
      const int o00 = yc0 * kWF + xc0;
      const int o01 = yc0 * kWF + xc1;
      const int o10 = yc1 * kWF + xc0;
      const int o11 = yc1 * kWF + xc1;
#pragma unroll
      for (int c = 0; c < kC; ++c) {
        const float* bc = fbase + (size_t)c * kFeatPix;
        float val = w00*bc[o00] + w01*bc[o01] + w10*bc[o10] + w11*bc[o11];
        acc[c] += val; accsq[c] += val*val;
      }
    }
  }

  // variance epilogue: counts == 8 per ref (ref row is repeat(arange(9),8))
  float* op = out + ((size_t)n * kC * kNPlanes + d) * kNPix + p;
#pragma unroll
  for (int c = 0; c < kC; ++c) {
    float mean = acc[c] * 0.125f;
    float msq  = accsq[c] * 0.125f;
    op[(size_t)c * (kNPlanes * kNPix)] = msq - mean * mean;
  }
}

extern "C" void kernel_launch(void* const* d_in, const int* in_sizes, int n_in,
                              void* d_out, int out_size, void* d_ws, size_t ws_size,
                              hipStream_t stream) {
  const float* feats  = (const float*)d_in[0];
  const float* rot    = (const float*)d_in[1];
  const float* tv     = (const float*)d_in[2];
  const float* Kmat   = (const float*)d_in[3];
  const int*   edges  = (const int*)d_in[4];
  float* out = (float*)d_out;

  const size_t packBytes = (size_t)kNImgs * kFeatPix * 2 * kC * sizeof(_Float16);  // 10.8 MB
  const int nMain = kNImgs * kPtsPerRef;            // 1,806,336
  const int gridMain = nMain / 256;                 // 7056 = 8 * 882

  if (ws_size >= packBytes) {
    _Float16* featsP = (_Float16*)d_ws;
    const int nP = kNImgs * kFeatPix;               // 112,896
    pack_feats_kernel<<<(nP + 255) / 256, 256, 0, stream>>>(feats, featsP);
    psv_var_kernel<true><<<gridMain, 256, 0, stream>>>(feats, featsP, rot, tv, Kmat, edges, out);
  } else {
    psv_var_kernel<false><<<gridMain, 256, 0, stream>>>(feats, nullptr, rot, tv, Kmat, edges, out);
  }
}

// Round 5
// 184.758 us; speedup vs baseline: 1.8564x; 1.8564x over previous
//
#include <hip/hip_runtime.h>

// ---- static config (matches reference) ----
constexpr int kNImgs   = 9;
constexpr int kC       = 24;
constexpr int kHF      = 112, kWF = 112;
constexpr int kHD      = 56,  kWD = 56;
constexpr int kNPix    = kHD * kWD;              // 3136
constexpr int kNPlanes = 64;
constexpr int kPtsPerRef = kNPlanes * kNPix;     // 200704 = 784 * 256
constexpr int kEdgesPerRef = 8;
constexpr int kNEdges  = kNImgs * kEdgesPerRef;  // 72
constexpr int kFeatPix = kHF * kWF;              // 12544
constexpr int kFeatPerImg = kC * kFeatPix;       // 301056

typedef _Float16 half8 __attribute__((ext_vector_type(8)));

// ---------- small 3x3 helpers ----------
__device__ inline void mm3(const float* A, const float* B, float* C) {
#pragma unroll
  for (int i = 0; i < 3; ++i)
#pragma unroll
    for (int j = 0; j < 3; ++j)
      C[i*3+j] = A[i*3+0]*B[0*3+j] + A[i*3+1]*B[1*3+j] + A[i*3+2]*B[2*3+j];
}

__device__ inline void inv3(const float* A, float* I) {
  float a=A[0],b=A[1],c=A[2],d=A[3],e=A[4],f=A[5],g=A[6],h=A[7],i=A[8];
  float c00 = e*i - f*h;
  float c01 = -(d*i - f*g);
  float c02 = d*h - e*g;
  float det = a*c00 + b*c01 + c*c02;
  float r = 1.0f / det;
  I[0] = c00*r;           I[1] = (c*h - b*i)*r;  I[2] = (b*f - c*e)*r;
  I[3] = c01*r;           I[4] = (a*i - c*g)*r;  I[5] = (c*d - a*f)*r;
  I[6] = c02*r;           I[7] = (b*g - a*h)*r;  I[8] = (a*e - b*d)*r;
}

// ---------- transpose+convert feats [N,C,HF,WF] f32 -> [N,HF,WF,C] f16 ----------
__global__ __launch_bounds__(256)
void transpose_feats_kernel(const float* __restrict__ f, _Float16* __restrict__ ft) {
  int idx = blockIdx.x * 256 + threadIdx.x;
  if (idx >= kNImgs * kFeatPerImg) return;
  int n  = idx / kFeatPerImg;
  int r  = idx - n * kFeatPerImg;
  int c  = r / kFeatPix;
  int yx = r - c * kFeatPix;
  ft[((size_t)n * kFeatPix + yx) * kC + c] = (_Float16)f[idx];
}

// ---------- main fused kernel ----------
// thread = one (ref n, plane d, pixel p) point; writes 24 channel variances.
// Per-ref edge dedup: duplicate (ref,src) edges contribute identical samples,
// so accumulate multiplicity * val instead of recomputing the gather.
template <bool TR>
__global__ __launch_bounds__(256)
void psv_var_kernel(const float* __restrict__ feats,      // [N,C,HF,WF] f32 (used if !TR)
                    const _Float16* __restrict__ featsT,  // [N,HF,WF,C] f16 (used if TR)
                    const float* __restrict__ rotmats,    // [N,3,3]
                    const float* __restrict__ tvecs,      // [N,3]
                    const float* __restrict__ Kmat,       // [N,3,3]
                    const int*   __restrict__ edges,      // [2,72]
                    float* __restrict__ out) {            // [N,C,D,HD,WD]
  __shared__ float sM[kEdgesPerRef][9];
  __shared__ float sB[kEdgesPerRef][3];
  __shared__ int   sSrc[kEdgesPerRef];
  __shared__ int   sUIdx[kEdgesPerRef];
  __shared__ float sMult[kEdgesPerRef];
  __shared__ int   sKU;

  // XCD-contiguous swizzle: 7056 blocks = 8 * 882 exactly -> bijective.
  const int nwg = gridDim.x;
  int bid = blockIdx.x;
  if ((nwg & 7) == 0) {
    const int cpx = nwg >> 3;
    bid = (bid & 7) * cpx + (bid >> 3);
  }

  const int tid = bid * 256 + threadIdx.x;
  const int n = tid / kPtsPerRef;  // block never straddles refs (200704 % 256 == 0)

  if (threadIdx.x < kEdgesPerRef) {
    const int e  = n * kEdgesPerRef + threadIdx.x;
    const int re = edges[e];            // ref row
    const int se = edges[kNEdges + e];  // src row
    sSrc[threadIdx.x] = se;

    const float* Rr = rotmats + re * 9;
    const float* Rs = rotmats + se * 9;
    const float* Kr = Kmat + re * 9;
    const float* Ks = Kmat + se * 9;
    const float* tr = tvecs + re * 3;
    const float* ts = tvecs + se * 3;

    float RrT[9];
#pragma unroll
    for (int i = 0; i < 3; ++i)
#pragma unroll
      for (int j = 0; j < 3; ++j) RrT[i*3+j] = Rr[j*3+i];

    float Kinv[9], A[9], T1[9], M[9];
    inv3(Kr, Kinv);
    mm3(Rs, RrT, A);       // A = R_src * R_ref^T
    mm3(A, Kinv, T1);
    mm3(Ks, T1, M);        // M = K_src * A * K_ref^-1

    float At0 = A[0]*tr[0] + A[1]*tr[1] + A[2]*tr[2];
    float At1 = A[3]*tr[0] + A[4]*tr[1] + A[5]*tr[2];
    float At2 = A[6]*tr[0] + A[7]*tr[1] + A[8]*tr[2];
    float bv0 = ts[0] - At0, bv1 = ts[1] - At1, bv2 = ts[2] - At2;
#pragma unroll
    for (int i = 0; i < 9; ++i) sM[threadIdx.x][i] = M[i];
#pragma unroll
    for (int i = 0; i < 3; ++i)
      sB[threadIdx.x][i] = Ks[i*3+0]*bv0 + Ks[i*3+1]*bv1 + Ks[i*3+2]*bv2;
  }
  __syncthreads();

  if (threadIdx.x == 0) {
    int k = 0;
    for (int j = 0; j < kEdgesPerRef; ++j) {
      const int s = sSrc[j];
      bool dup = false;
      for (int i = 0; i < k; ++i) {
        if (sSrc[sUIdx[i]] == s) { sMult[i] += 1.0f; dup = true; break; }
      }
      if (!dup) { sUIdx[k] = j; sMult[k] = 1.0f; ++k; }
    }
    sKU = k;
  }
  __syncthreads();

  const int local = tid - n * kPtsPerRef;
  const int d = local / kNPix;
  const int p = local - d * kNPix;
  const int h = p / kWD;
  const int w = p - h * kWD;

  const float u = (float)w * (447.0f / 55.0f);   // linspace(0,447,56)
  const float v = (float)h * (447.0f / 55.0f);
  const float depth = 0.5f + 0.05f * (float)d;

  float acc[kC], accsq[kC];
#pragma unroll
  for (int c = 0; c < kC; ++c) { acc[c] = 0.0f; accsq[c] = 0.0f; }

  const int kU = sKU;
#pragma unroll 2
  for (int jj = 0; jj < kU; ++jj) {
    const int j = sUIdx[jj];
    const float mult = sMult[jj];
    const float* M = sM[j];
    const float px = depth * (M[0]*u + M[1]*v + M[2]) + sB[j][0];
    const float py = depth * (M[3]*u + M[4]*v + M[5]) + sB[j][1];
    const float pz = depth * (M[6]*u + M[7]*v + M[8]) + sB[j][2];
    const float rz = 1.0f / (fabsf(pz) + 1e-8f);

    // x = (px/z) * 111/447  (align_corners=True, folded constants)
    const float x = px * rz * (111.0f / 447.0f);
    const float y = py * rz * (111.0f / 447.0f);

    const float x0 = floorf(x), y0 = floorf(y);
    const float wx = x - x0, wy = y - y0;
    const bool vx0 = (x0 >= 0.0f)  && (x0 <= 111.0f);
    const bool vx1 = (x0 >= -1.0f) && (x0 <= 110.0f);
    const bool vy0 = (y0 >= 0.0f)  && (y0 <= 111.0f);
    const bool vy1 = (y0 >= -1.0f) && (y0 <= 110.0f);
    const float w00 = (vx0 && vy0) ? (1.0f - wx) * (1.0f - wy) : 0.0f;
    const float w01 = (vx1 && vy0) ? wx * (1.0f - wy) : 0.0f;
    const float w10 = (vx0 && vy1) ? (1.0f - wx) * wy : 0.0f;
    const float w11 = (vx1 && vy1) ? wx * wy : 0.0f;

    const int xc0 = (int)fminf(fmaxf(x0,        0.0f), 111.0f);
    const int xc1 = (int)fminf(fmaxf(x0 + 1.0f, 0.0f), 111.0f);
    const int yc0 = (int)fminf(fmaxf(y0,        0.0f), 111.0f);
    const int yc1 = (int)fminf(fmaxf(y0 + 1.0f, 0.0f), 111.0f);

    const int src = sSrc[j];
    if constexpr (TR) {
      const _Float16* base = featsT + (size_t)src * kFeatPix * kC;
      const int o00 = (yc0 * kWF + xc0) * kC;
      const int o01 = (yc0 * kWF + xc1) * kC;
      const int o10 = (yc1 * kWF + xc0) * kC;
      const int o11 = (yc1 * kWF + xc1) * kC;
#pragma unroll
      for (int i = 0; i < kC / 8; ++i) {          // 3 chunks of 8 f16 channels
        const half8 f00 = *(const half8*)(base + o00 + 8*i);
        const half8 f01 = *(const half8*)(base + o01 + 8*i);
        const half8 f10 = *(const half8*)(base + o10 + 8*i);
        const half8 f11 = *(const half8*)(base + o11 + 8*i);
#pragma unroll
        for (int k = 0; k < 8; ++k) {
          float val = w00 * (float)f00[k] + w01 * (float)f01[k]
                    + w10 * (float)f10[k] + w11 * (float)f11[k];
          const int c = 8*i + k;
          const float mval = mult * val;
          acc[c] += mval;
          accsq[c] = __builtin_fmaf(mval, val, accsq[c]);
        }
      }
    } else {
      const float* base = feats + (size_t)src * kFeatPerImg;
      const int o00 = yc0 * kWF + xc0;
      const int o01 = yc0 * kWF + xc1;
      const int o10 = yc1 * kWF + xc0;
      const int o11 = yc1 * kWF + xc1;
#pragma unroll
      for (int c = 0; c < kC; ++c) {
        const float* bc = base + c * kFeatPix;
        float val = w00*bc[o00] + w01*bc[o01] + w10*bc[o10] + w11*bc[o11];
        const float mval = mult * val;
        acc[c] += mval;
        accsq[c] = __builtin_fmaf(mval, val, accsq[c]);
      }
    }
  }

  // variance epilogue: counts == 8 per ref (ref row is repeat(arange(9),8))
  float* op = out + ((size_t)n * kC * kNPlanes + d) * kNPix + p;
#pragma unroll
  for (int c = 0; c < kC; ++c) {
    float mean = acc[c] * 0.125f;
    float msq  = accsq[c] * 0.125f;
    op[(size_t)c * (kNPlanes * kNPix)] = msq - mean * mean;
  }
}

extern "C" void kernel_launch(void* const* d_in, const int* in_sizes, int n_in,
                              void* d_out, int out_size, void* d_ws, size_t ws_size,
                              hipStream_t stream) {
  const float* feats  = (const float*)d_in[0];
  const float* rot    = (const float*)d_in[1];
  const float* tv     = (const float*)d_in[2];
  const float* Kmat   = (const float*)d_in[3];
  const int*   edges  = (const int*)d_in[4];
  float* out = (float*)d_out;

  const size_t featsTBytes = (size_t)kNImgs * kFeatPix * kC * sizeof(_Float16);  // 5.4 MB
  const int nMain = kNImgs * kPtsPerRef;            // 1,806,336
  const int gridMain = nMain / 256;                 // 7056 = 8 * 882

  if (ws_size >= featsTBytes) {
    _Float16* featsT = (_Float16*)d_ws;
    const int nT = kNImgs * kFeatPerImg;            // 2,709,504
    transpose_feats_kernel<<<(nT + 255) / 256, 256, 0, stream>>>(feats, featsT);
    psv_var_kernel<true><<<gridMain, 256, 0, stream>>>(feats, featsT, rot, tv, Kmat, edges, out);
  } else {
    psv_var_kernel<false><<<gridMain, 256, 0, stream>>>(feats, nullptr, rot, tv, Kmat, edges, out);
  }
}

// Round 6
// 171.225 us; speedup vs baseline: 2.0031x; 1.0790x over previous
//
#include <hip/hip_runtime.h>

// ---- static config (matches reference) ----
constexpr int kNImgs   = 9;
constexpr int kC       = 24;
constexpr int kHF      = 112, kWF = 112;
constexpr int kHD      = 56,  kWD = 56;
constexpr int kNPix    = kHD * kWD;              // 3136
constexpr int kNPlanes = 64;
constexpr int kPtsPerRef = kNPlanes * kNPix;     // 200704
constexpr int kEdgesPerRef = 8;
constexpr int kNEdges  = kNImgs * kEdgesPerRef;  // 72
constexpr int kFeatPix = kHF * kWF;              // 12544
constexpr int kFeatPerImg = kC * kFeatPix;       // 301056

// block geometry: 1024 threads = 32 d (lane-major) x 32 p
constexpr int kDTile = 32, kPTile = 32;
constexpr int kDHalves = kNPlanes / kDTile;      // 2
constexpr int kPGroups = kNPix / kPTile;         // 98
constexpr int kBlocksPerRef = kDHalves * kPGroups; // 196

typedef _Float16 half8 __attribute__((ext_vector_type(8)));

// ---------- small 3x3 helpers ----------
__device__ inline void mm3(const float* A, const float* B, float* C) {
#pragma unroll
  for (int i = 0; i < 3; ++i)
#pragma unroll
    for (int j = 0; j < 3; ++j)
      C[i*3+j] = A[i*3+0]*B[0*3+j] + A[i*3+1]*B[1*3+j] + A[i*3+2]*B[2*3+j];
}

__device__ inline void inv3(const float* A, float* I) {
  float a=A[0],b=A[1],c=A[2],d=A[3],e=A[4],f=A[5],g=A[6],h=A[7],i=A[8];
  float c00 = e*i - f*h;
  float c01 = -(d*i - f*g);
  float c02 = d*h - e*g;
  float det = a*c00 + b*c01 + c*c02;
  float r = 1.0f / det;
  I[0] = c00*r;           I[1] = (c*h - b*i)*r;  I[2] = (b*f - c*e)*r;
  I[3] = c01*r;           I[4] = (a*i - c*g)*r;  I[5] = (c*d - a*f)*r;
  I[6] = c02*r;           I[7] = (b*g - a*h)*r;  I[8] = (a*e - b*d)*r;
}

// ---------- transpose+convert feats [N,C,HF,WF] f32 -> [N,HF,WF,C] f16 ----------
__global__ __launch_bounds__(256)
void transpose_feats_kernel(const float* __restrict__ f, _Float16* __restrict__ ft) {
  int idx = blockIdx.x * 256 + threadIdx.x;
  if (idx >= kNImgs * kFeatPerImg) return;
  int n  = idx / kFeatPerImg;
  int r  = idx - n * kFeatPerImg;
  int c  = r / kFeatPix;
  int yx = r - c * kFeatPix;
  ft[((size_t)n * kFeatPix + yx) * kC + c] = (_Float16)f[idx];
}

// ---------- main fused kernel ----------
// block = (ref n, d-half, p-group); thread = (d_sub, p_sub), lanes d-major so
// a wave's gathers walk an epipolar segment (sub-pixel step -> line sharing).
// LDS transpose epilogue restores 32-px coalesced stores.
template <bool TR>
__global__ __launch_bounds__(1024, 4)
void psv_var_kernel(const float* __restrict__ feats,      // [N,C,HF,WF] f32 (!TR)
                    const _Float16* __restrict__ featsT,  // [N,HF,WF,C] f16 (TR)
                    const float* __restrict__ rotmats,    // [N,3,3]
                    const float* __restrict__ tvecs,      // [N,3]
                    const float* __restrict__ Kmat,       // [N,3,3]
                    const int*   __restrict__ edges,      // [2,72]
                    float* __restrict__ out) {            // [N,C,D,HD,WD]
  __shared__ float sM[kEdgesPerRef][9];
  __shared__ float sB[kEdgesPerRef][3];
  __shared__ int   sSrc[kEdgesPerRef];
  __shared__ int   sUIdx[kEdgesPerRef];
  __shared__ float sMult[kEdgesPerRef];
  __shared__ int   sKU;
  __shared__ float sT[4][kDTile][kPTile + 1];   // transpose buffer, +1 pad

  // bijective XCD-chunk swizzle (works for any gridDim, m204 formula)
  const int nwg = gridDim.x;
  const int orig = blockIdx.x;
  const int q = nwg >> 3, r8 = nwg & 7;
  const int xcd = orig & 7, lin = orig >> 3;
  const int bid = ((xcd < r8) ? xcd * (q + 1) : r8 * (q + 1) + (xcd - r8) * q) + lin;

  const int n     = bid / kBlocksPerRef;
  const int rem   = bid - n * kBlocksPerRef;
  const int dHalf = rem / kPGroups;
  const int pG    = rem - dHalf * kPGroups;

  const int t = threadIdx.x;

  if (t < kEdgesPerRef) {
    const int e  = n * kEdgesPerRef + t;
    const int re = edges[e];            // ref row
    const int se = edges[kNEdges + e];  // src row
    sSrc[t] = se;

    const float* Rr = rotmats + re * 9;
    const float* Rs = rotmats + se * 9;
    const float* Kr = Kmat + re * 9;
    const float* Ks = Kmat + se * 9;
    const float* tr = tvecs + re * 3;
    const float* ts = tvecs + se * 3;

    float RrT[9];
#pragma unroll
    for (int i = 0; i < 3; ++i)
#pragma unroll
      for (int j = 0; j < 3; ++j) RrT[i*3+j] = Rr[j*3+i];

    float Kinv[9], A[9], T1[9], M[9];
    inv3(Kr, Kinv);
    mm3(Rs, RrT, A);       // A = R_src * R_ref^T
    mm3(A, Kinv, T1);
    mm3(Ks, T1, M);        // M = K_src * A * K_ref^-1

    float At0 = A[0]*tr[0] + A[1]*tr[1] + A[2]*tr[2];
    float At1 = A[3]*tr[0] + A[4]*tr[1] + A[5]*tr[2];
    float At2 = A[6]*tr[0] + A[7]*tr[1] + A[8]*tr[2];
    float bv0 = ts[0] - At0, bv1 = ts[1] - At1, bv2 = ts[2] - At2;
#pragma unroll
    for (int i = 0; i < 9; ++i) sM[t][i] = M[i];
#pragma unroll
    for (int i = 0; i < 3; ++i)
      sB[t][i] = Ks[i*3+0]*bv0 + Ks[i*3+1]*bv1 + Ks[i*3+2]*bv2;
  }
  __syncthreads();

  if (t == 0) {
    int k = 0;
    for (int j = 0; j < kEdgesPerRef; ++j) {
      const int s = sSrc[j];
      bool dup = false;
      for (int i = 0; i < k; ++i) {
        if (sSrc[sUIdx[i]] == s) { sMult[i] += 1.0f; dup = true; break; }
      }
      if (!dup) { sUIdx[k] = j; sMult[k] = 1.0f; ++k; }
    }
    sKU = k;
  }
  __syncthreads();

  // d-major lane mapping
  const int dsub = t & 31;
  const int psub = t >> 5;
  const int d = dHalf * kDTile + dsub;
  const int p = pG * kPTile + psub;
  const int h = p / kWD;
  const int w = p - h * kWD;

  const float u = (float)w * (447.0f / 55.0f);   // linspace(0,447,56)
  const float v = (float)h * (447.0f / 55.0f);
  const float depth = 0.5f + 0.05f * (float)d;

  float acc[kC], accsq[kC];
#pragma unroll
  for (int c = 0; c < kC; ++c) { acc[c] = 0.0f; accsq[c] = 0.0f; }

  const int kU = sKU;
#pragma unroll 2
  for (int jj = 0; jj < kU; ++jj) {
    const int j = sUIdx[jj];
    const float mult = sMult[jj];
    const float* M = sM[j];
    const float px = depth * (M[0]*u + M[1]*v + M[2]) + sB[j][0];
    const float py = depth * (M[3]*u + M[4]*v + M[5]) + sB[j][1];
    const float pz = depth * (M[6]*u + M[7]*v + M[8]) + sB[j][2];
    const float rz = 1.0f / (fabsf(pz) + 1e-8f);

    const float x = px * rz * (111.0f / 447.0f);
    const float y = py * rz * (111.0f / 447.0f);

    const float x0 = floorf(x), y0 = floorf(y);
    const float wx = x - x0, wy = y - y0;
    const bool vx0 = (x0 >= 0.0f)  && (x0 <= 111.0f);
    const bool vx1 = (x0 >= -1.0f) && (x0 <= 110.0f);
    const bool vy0 = (y0 >= 0.0f)  && (y0 <= 111.0f);
    const bool vy1 = (y0 >= -1.0f) && (y0 <= 110.0f);
    const float w00 = (vx0 && vy0) ? (1.0f - wx) * (1.0f - wy) : 0.0f;
    const float w01 = (vx1 && vy0) ? wx * (1.0f - wy) : 0.0f;
    const float w10 = (vx0 && vy1) ? (1.0f - wx) * wy : 0.0f;
    const float w11 = (vx1 && vy1) ? wx * wy : 0.0f;

    const int xc0 = (int)fminf(fmaxf(x0,        0.0f), 111.0f);
    const int xc1 = (int)fminf(fmaxf(x0 + 1.0f, 0.0f), 111.0f);
    const int yc0 = (int)fminf(fmaxf(y0,        0.0f), 111.0f);
    const int yc1 = (int)fminf(fmaxf(y0 + 1.0f, 0.0f), 111.0f);

    const int src = sSrc[j];
    if constexpr (TR) {
      const _Float16* base = featsT + (size_t)src * kFeatPix * kC;
      const int o00 = (yc0 * kWF + xc0) * kC;
      const int o01 = (yc0 * kWF + xc1) * kC;
      const int o10 = (yc1 * kWF + xc0) * kC;
      const int o11 = (yc1 * kWF + xc1) * kC;
#pragma unroll
      for (int i = 0; i < kC / 8; ++i) {          // 3 chunks of 8 f16 channels
        const half8 f00 = *(const half8*)(base + o00 + 8*i);
        const half8 f01 = *(const half8*)(base + o01 + 8*i);
        const half8 f10 = *(const half8*)(base + o10 + 8*i);
        const half8 f11 = *(const half8*)(base + o11 + 8*i);
#pragma unroll
        for (int k = 0; k < 8; ++k) {
          float val = w00 * (float)f00[k] + w01 * (float)f01[k]
                    + w10 * (float)f10[k] + w11 * (float)f11[k];
          const int c = 8*i + k;
          const float mval = mult * val;
          acc[c] += mval;
          accsq[c] = __builtin_fmaf(mval, val, accsq[c]);
        }
      }
    } else {
      const float* base = feats + (size_t)src * kFeatPerImg;
      const int o00 = yc0 * kWF + xc0;
      const int o01 = yc0 * kWF + xc1;
      const int o10 = yc1 * kWF + xc0;
      const int o11 = yc1 * kWF + xc1;
#pragma unroll
      for (int c = 0; c < kC; ++c) {
        const float* bc = base + c * kFeatPix;
        float val = w00*bc[o00] + w01*bc[o01] + w10*bc[o10] + w11*bc[o11];
        const float mval = mult * val;
        acc[c] += mval;
        accsq[c] = __builtin_fmaf(mval, val, accsq[c]);
      }
    }
  }

  // ---- epilogue: LDS transpose (d-major lanes -> p-coalesced stores) ----
  const int pp2 = t & 31;          // store-side pixel index (consecutive per lane)
  const int dd2 = t >> 5;          // store-side depth index
  const size_t outBase = (size_t)n * kC * (size_t)kPtsPerRef;
#pragma unroll
  for (int ch = 0; ch < kC / 4; ++ch) {
    __syncthreads();               // protect previous chunk's reads
#pragma unroll
    for (int cc = 0; cc < 4; ++cc) {
      const int c = ch * 4 + cc;
      const float mean = acc[c] * 0.125f;
      const float msq  = accsq[c] * 0.125f;
      sT[cc][dsub][psub] = msq - mean * mean;
    }
    __syncthreads();
#pragma unroll
    for (int cc = 0; cc < 4; ++cc) {
      const int c = ch * 4 + cc;
      out[outBase + ((size_t)c * kNPlanes + (dHalf * kDTile + dd2)) * kNPix
          + pG * kPTile + pp2] = sT[cc][dd2][pp2];
    }
  }
}

extern "C" void kernel_launch(void* const* d_in, const int* in_sizes, int n_in,
                              void* d_out, int out_size, void* d_ws, size_t ws_size,
                              hipStream_t stream) {
  const float* feats  = (const float*)d_in[0];
  const float* rot    = (const float*)d_in[1];
  const float* tv     = (const float*)d_in[2];
  const float* Kmat   = (const float*)d_in[3];
  const int*   edges  = (const int*)d_in[4];
  float* out = (float*)d_out;

  const size_t featsTBytes = (size_t)kNImgs * kFeatPix * kC * sizeof(_Float16);  // 5.4 MB
  const int gridMain = kNImgs * kBlocksPerRef;     // 1764 blocks of 1024 threads

  if (ws_size >= featsTBytes) {
    _Float16* featsT = (_Float16*)d_ws;
    const int nT = kNImgs * kFeatPerImg;           // 2,709,504
    transpose_feats_kernel<<<(nT + 255) / 256, 256, 0, stream>>>(feats, featsT);
    psv_var_kernel<true><<<gridMain, 1024, 0, stream>>>(feats, featsT, rot, tv, Kmat, edges, out);
  } else {
    psv_var_kernel<false><<<gridMain, 1024, 0, stream>>>(feats, nullptr, rot, tv, Kmat, edges, out);
  }
}

// Round 7
// 155.657 us; speedup vs baseline: 2.2035x; 1.1000x over previous
//
#include <hip/hip_runtime.h>

// ---- static config (matches reference) ----
constexpr int kNImgs   = 9;
constexpr int kC       = 24;
constexpr int kHF      = 112, kWF = 112;
constexpr int kHD      = 56,  kWD = 56;
constexpr int kNPix    = kHD * kWD;              // 3136
constexpr int kNPlanes = 64;
constexpr int kPtsPerRef = kNPlanes * kNPix;     // 200704
constexpr int kEdgesPerRef = 8;
constexpr int kNEdges  = kNImgs * kEdgesPerRef;  // 72
constexpr int kFeatPix = kHF * kWF;              // 12544
constexpr int kFeatPerImg = kC * kFeatPix;       // 301056

// block geometry: 512 threads = 32 d (lane-major) x 16 p
constexpr int kDTile = 32, kPTile = 16;
constexpr int kDHalves = kNPlanes / kDTile;        // 2
constexpr int kPGroups = kNPix / kPTile;           // 196
constexpr int kBlocksPerRef = kDHalves * kPGroups; // 392

typedef _Float16 half8  __attribute__((ext_vector_type(8)));
typedef _Float16 half2v __attribute__((ext_vector_type(2)));

#if __has_builtin(__builtin_amdgcn_fdot2)
__device__ inline float fdot2(half2v a, half2v b, float c) {
  return __builtin_amdgcn_fdot2(a, b, c, false);
}
#else
__device__ inline float fdot2(half2v a, half2v b, float c) {
  return c + (float)a[0] * (float)b[0] + (float)a[1] * (float)b[1];
}
#endif

// ---------- small 3x3 helpers ----------
__device__ inline void mm3(const float* A, const float* B, float* C) {
#pragma unroll
  for (int i = 0; i < 3; ++i)
#pragma unroll
    for (int j = 0; j < 3; ++j)
      C[i*3+j] = A[i*3+0]*B[0*3+j] + A[i*3+1]*B[1*3+j] + A[i*3+2]*B[2*3+j];
}

__device__ inline void inv3(const float* A, float* I) {
  float a=A[0],b=A[1],c=A[2],d=A[3],e=A[4],f=A[5],g=A[6],h=A[7],i=A[8];
  float c00 = e*i - f*h;
  float c01 = -(d*i - f*g);
  float c02 = d*h - e*g;
  float det = a*c00 + b*c01 + c*c02;
  float r = 1.0f / det;
  I[0] = c00*r;           I[1] = (c*h - b*i)*r;  I[2] = (b*f - c*e)*r;
  I[3] = c01*r;           I[4] = (a*i - c*g)*r;  I[5] = (c*d - a*f)*r;
  I[6] = c02*r;           I[7] = (b*g - a*h)*r;  I[8] = (a*e - b*d)*r;
}

// ---------- transpose+convert feats [N,C,HF,WF] f32 -> [N,HF,WF,C] f16 ----------
__global__ __launch_bounds__(256)
void transpose_feats_kernel(const float* __restrict__ f, _Float16* __restrict__ ft) {
  int idx = blockIdx.x * 256 + threadIdx.x;
  if (idx >= kNImgs * kFeatPerImg) return;
  int n  = idx / kFeatPerImg;
  int r  = idx - n * kFeatPerImg;
  int c  = r / kFeatPix;
  int yx = r - c * kFeatPix;
  ft[((size_t)n * kFeatPix + yx) * kC + c] = (_Float16)f[idx];
}

// ---------- main fused kernel ----------
// block = (ref n, d-half, p-group); lanes d-major (wave = 32 d x 2 p) so a
// wave's gathers walk an epipolar segment (sub-pixel step -> line sharing).
// Inner loop: register-packed half2 pairs + v_dot2_f32_f16 (f32 accumulate).
// LDS transpose epilogue restores p-coalesced stores.
template <bool TR>
__global__ __launch_bounds__(512)
void psv_var_kernel(const float* __restrict__ feats,      // [N,C,HF,WF] f32 (!TR)
                    const _Float16* __restrict__ featsT,  // [N,HF,WF,C] f16 (TR)
                    const float* __restrict__ rotmats,    // [N,3,3]
                    const float* __restrict__ tvecs,      // [N,3]
                    const float* __restrict__ Kmat,       // [N,3,3]
                    const int*   __restrict__ edges,      // [2,72]
                    float* __restrict__ out) {            // [N,C,D,HD,WD]
  __shared__ float sM[kEdgesPerRef][9];
  __shared__ float sB[kEdgesPerRef][3];
  __shared__ int   sSrc[kEdgesPerRef];
  __shared__ int   sUIdx[kEdgesPerRef];
  __shared__ float sMult[kEdgesPerRef];
  __shared__ int   sKU;
  __shared__ float sT[4][kDTile][kPTile + 1];   // transpose buffer, +1 pad

  // bijective XCD-chunk swizzle (m204 formula; works for any gridDim)
  const int nwg = gridDim.x;
  const int orig = blockIdx.x;
  const int q = nwg >> 3, r8 = nwg & 7;
  const int xcd = orig & 7, lin = orig >> 3;
  const int bid = ((xcd < r8) ? xcd * (q + 1) : r8 * (q + 1) + (xcd - r8) * q) + lin;

  const int n     = bid / kBlocksPerRef;
  const int rem   = bid - n * kBlocksPerRef;
  const int dHalf = rem / kPGroups;
  const int pG    = rem - dHalf * kPGroups;

  const int t = threadIdx.x;

  if (t < kEdgesPerRef) {
    const int e  = n * kEdgesPerRef + t;
    const int re = edges[e];            // ref row
    const int se = edges[kNEdges + e];  // src row
    sSrc[t] = se;

    const float* Rr = rotmats + re * 9;
    const float* Rs = rotmats + se * 9;
    const float* Kr = Kmat + re * 9;
    const float* Ks = Kmat + se * 9;
    const float* tr = tvecs + re * 3;
    const float* ts = tvecs + se * 3;

    float RrT[9];
#pragma unroll
    for (int i = 0; i < 3; ++i)
#pragma unroll
      for (int j = 0; j < 3; ++j) RrT[i*3+j] = Rr[j*3+i];

    float Kinv[9], A[9], T1[9], M[9];
    inv3(Kr, Kinv);
    mm3(Rs, RrT, A);       // A = R_src * R_ref^T
    mm3(A, Kinv, T1);
    mm3(Ks, T1, M);        // M = K_src * A * K_ref^-1

    float At0 = A[0]*tr[0] + A[1]*tr[1] + A[2]*tr[2];
    float At1 = A[3]*tr[0] + A[4]*tr[1] + A[5]*tr[2];
    float At2 = A[6]*tr[0] + A[7]*tr[1] + A[8]*tr[2];
    float bv0 = ts[0] - At0, bv1 = ts[1] - At1, bv2 = ts[2] - At2;
#pragma unroll
    for (int i = 0; i < 9; ++i) sM[t][i] = M[i];
#pragma unroll
    for (int i = 0; i < 3; ++i)
      sB[t][i] = Ks[i*3+0]*bv0 + Ks[i*3+1]*bv1 + Ks[i*3+2]*bv2;
  }
  __syncthreads();

  if (t == 0) {
    int k = 0;
    for (int j = 0; j < kEdgesPerRef; ++j) {
      const int s = sSrc[j];
      bool dup = false;
      for (int i = 0; i < k; ++i) {
        if (sSrc[sUIdx[i]] == s) { sMult[i] += 1.0f; dup = true; break; }
      }
      if (!dup) { sUIdx[k] = j; sMult[k] = 1.0f; ++k; }
    }
    sKU = k;
  }
  __syncthreads();

  // d-major lane mapping
  const int dsub = t & 31;
  const int psub = t >> 5;
  const int d = dHalf * kDTile + dsub;
  const int p = pG * kPTile + psub;
  const int h = p / kWD;
  const int w = p - h * kWD;

  const float u = (float)w * (447.0f / 55.0f);   // linspace(0,447,56)
  const float v = (float)h * (447.0f / 55.0f);
  const float depth = 0.5f + 0.05f * (float)d;

  float acc[kC], accsq[kC];
#pragma unroll
  for (int c = 0; c < kC; ++c) { acc[c] = 0.0f; accsq[c] = 0.0f; }

  const int kU = sKU;
#pragma unroll 2
  for (int jj = 0; jj < kU; ++jj) {
    const int j = sUIdx[jj];
    const float mult = sMult[jj];
    const float* M = sM[j];
    const float px = depth * (M[0]*u + M[1]*v + M[2]) + sB[j][0];
    const float py = depth * (M[3]*u + M[4]*v + M[5]) + sB[j][1];
    const float pz = depth * (M[6]*u + M[7]*v + M[8]) + sB[j][2];
    const float rz = 1.0f / (fabsf(pz) + 1e-8f);

    const float x = px * rz * (111.0f / 447.0f);
    const float y = py * rz * (111.0f / 447.0f);

    const float x0 = floorf(x), y0 = floorf(y);
    const float wx = x - x0, wy = y - y0;
    const bool vx0 = (x0 >= 0.0f)  && (x0 <= 111.0f);
    const bool vx1 = (x0 >= -1.0f) && (x0 <= 110.0f);
    const bool vy0 = (y0 >= 0.0f)  && (y0 <= 111.0f);
    const bool vy1 = (y0 >= -1.0f) && (y0 <= 110.0f);
    const float w00 = (vx0 && vy0) ? (1.0f - wx) * (1.0f - wy) : 0.0f;
    const float w01 = (vx1 && vy0) ? wx * (1.0f - wy) : 0.0f;
    const float w10 = (vx0 && vy1) ? (1.0f - wx) * wy : 0.0f;
    const float w11 = (vx1 && vy1) ? wx * wy : 0.0f;

    const int xc0 = (int)fminf(fmaxf(x0,        0.0f), 111.0f);
    const int xc1 = (int)fminf(fmaxf(x0 + 1.0f, 0.0f), 111.0f);
    const int yc0 = (int)fminf(fmaxf(y0,        0.0f), 111.0f);
    const int yc1 = (int)fminf(fmaxf(y0 + 1.0f, 0.0f), 111.0f);

    const int src = sSrc[j];
    if constexpr (TR) {
      // f16 weight pairs (row0: w00,w01 ; row1: w10,w11) — f32 accumulation
      // inside fdot2, so only weight rounding is f16 (validated R4: absmax
      // unchanged at 0.015625).
      const half2v wr0 = {(_Float16)w00, (_Float16)w01};
      const half2v wr1 = {(_Float16)w10, (_Float16)w11};
      const _Float16* base = featsT + (size_t)src * kFeatPix * kC;
      const int o00 = (yc0 * kWF + xc0) * kC;
      const int o01 = (yc0 * kWF + xc1) * kC;
      const int o10 = (yc1 * kWF + xc0) * kC;
      const int o11 = (yc1 * kWF + xc1) * kC;
#pragma unroll
      for (int i = 0; i < kC / 8; ++i) {          // 3 chunks of 8 f16 channels
        const half8 f00 = *(const half8*)(base + o00 + 8*i);
        const half8 f01 = *(const half8*)(base + o01 + 8*i);
        const half8 f10 = *(const half8*)(base + o10 + 8*i);
        const half8 f11 = *(const half8*)(base + o11 + 8*i);
#pragma unroll
        for (int k = 0; k < 8; ++k) {
          const half2v a0 = {f00[k], f01[k]};     // register pack (v_perm)
          const half2v a1 = {f10[k], f11[k]};
          const float val = fdot2(a1, wr1, fdot2(a0, wr0, 0.0f));
          const int c = 8*i + k;
          const float mval = mult * val;
          acc[c] += mval;
          accsq[c] = __builtin_fmaf(mval, val, accsq[c]);
        }
      }
    } else {
      const float* base = feats + (size_t)src * kFeatPerImg;
      const int o00 = yc0 * kWF + xc0;
      const int o01 = yc0 * kWF + xc1;
      const int o10 = yc1 * kWF + xc0;
      const int o11 = yc1 * kWF + xc1;
#pragma unroll
      for (int c = 0; c < kC; ++c) {
        const float* bc = base + c * kFeatPix;
        float val = w00*bc[o00] + w01*bc[o01] + w10*bc[o10] + w11*bc[o11];
        const float mval = mult * val;
        acc[c] += mval;
        accsq[c] = __builtin_fmaf(mval, val, accsq[c]);
      }
    }
  }

  // ---- epilogue: LDS transpose (d-major lanes -> p-coalesced stores) ----
  const int pp2 = t & (kPTile - 1);   // store-side pixel index
  const int dd2 = t >> 4;             // store-side depth index (0..31)
  const size_t outBase = (size_t)n * kC * (size_t)kPtsPerRef;
#pragma unroll
  for (int ch = 0; ch < kC / 4; ++ch) {
    __syncthreads();               // protect previous chunk's reads
#pragma unroll
    for (int cc = 0; cc < 4; ++cc) {
      const int c = ch * 4 + cc;
      const float mean = acc[c] * 0.125f;
      const float msq  = accsq[c] * 0.125f;
      sT[cc][dsub][psub] = msq - mean * mean;
    }
    __syncthreads();
#pragma unroll
    for (int cc = 0; cc < 4; ++cc) {
      const int c = ch * 4 + cc;
      out[outBase + ((size_t)c * kNPlanes + (dHalf * kDTile + dd2)) * kNPix
          + pG * kPTile + pp2] = sT[cc][dd2][pp2];
    }
  }
}

extern "C" void kernel_launch(void* const* d_in, const int* in_sizes, int n_in,
                              void* d_out, int out_size, void* d_ws, size_t ws_size,
                              hipStream_t stream) {
  const float* feats  = (const float*)d_in[0];
  const float* rot    = (const float*)d_in[1];
  const float* tv     = (const float*)d_in[2];
  const float* Kmat   = (const float*)d_in[3];
  const int*   edges  = (const int*)d_in[4];
  float* out = (float*)d_out;

  const size_t featsTBytes = (size_t)kNImgs * kFeatPix * kC * sizeof(_Float16);  // 5.4 MB
  const int gridMain = kNImgs * kBlocksPerRef;     // 3528 blocks of 512 threads

  if (ws_size >= featsTBytes) {
    _Float16* featsT = (_Float16*)d_ws;
    const int nT = kNImgs * kFeatPerImg;           // 2,709,504
    transpose_feats_kernel<<<(nT + 255) / 256, 256, 0, stream>>>(feats, featsT);
    psv_var_kernel<true><<<gridMain, 512, 0, stream>>>(feats, featsT, rot, tv, Kmat, edges, out);
  } else {
    psv_var_kernel<false><<<gridMain, 512, 0, stream>>>(feats, nullptr, rot, tv, Kmat, edges, out);
  }
}